// Round 12
// baseline (49.237 us; speedup 1.0000x reference)
//
#include <hip/hip_runtime.h>
#include <hip/hip_bf16.h>
#include <math.h>

#define IN_C 31
#define OUT_C 31
#define NPIX 16384
#define UW_OFF 7688
#define RW_OFF 8649
#define PART_OFF (640 * 1024)  // ws byte offset of partial-Y buffers (weights use 620 KB)
#define CHUNK_BYTES 20480      // 20 KB of packed B-fragments per input channel i

typedef __attribute__((ext_vector_type(8))) short bf16x8;
typedef __attribute__((ext_vector_type(4))) float f32x4;

__device__ inline short f2bf(float f) {
    union { __hip_bfloat16 h; short s; } cv;
    cv.h = __float2bfloat16(f);   // RNE
    return cv.s;
}

// ---------------- prep: pack generator weights into MFMA B-fragment chunks ----
// ws layout: for i in [0,31): 20 chunks of 1 KB (20 KB per i, 620 KB total):
//   pairs 0..7 : spline B, chunk = kc*2 + nt  (kc in [0,8), nt in {0,1})
//   pair 8 (chunks 16,17) : uw B;  pair 9 (chunks 18,19) : rw B
__global__ __launch_bounds__(64) void kan_prep_kernel(
    const float* __restrict__ gw, const float* __restrict__ gb,
    unsigned short* __restrict__ ws)
{
    const int blk = blockIdx.x;          // 31*20 = 620
    const int i   = blk / 20;
    const int ch  = blk % 20;
    const int l   = threadIdx.x;
    const int col = l & 15;
    const int krow = l >> 4;
    const int o = (ch & 1) * 16 + col;

    int p;
    if (ch < 16)      p = (i * 31 + o) * 8 + (ch >> 1);
    else if (ch < 18) p = UW_OFF + i * 31 + o;
    else              p = RW_OFF + i * 31 + o;

    bf16x8 v8;
#pragma unroll
    for (int j = 0; j < 8; ++j) {
        const int c = krow * 8 + j;
        float v = 0.f;
        if (o < OUT_C) v = (c < IN_C) ? gw[p * 31 + c] : gb[p];
        v8[j] = f2bf(v);
    }
    ((bf16x8*)ws)[blk * 64 + l] = v8;
}

// Stage one i's 20 KB chunk into LDS via async global->LDS DMA, 512 threads:
// 1280 16B slots: 2 full passes (1024) + waves 0..3 take the tail (256).
__device__ __forceinline__ void stage_i(const unsigned char* wsrc,
                                        unsigned char* ldst, int t) {
#pragma unroll
    for (int k = 0; k < 2; ++k) {
        const int off = (k * 512 + t) * 16;
        __builtin_amdgcn_global_load_lds(
            (const __attribute__((address_space(1))) unsigned int*)(wsrc + off),
            (__attribute__((address_space(3))) unsigned int*)(ldst + off),
            16, 0, 0);
    }
    if (t < 256) {                       // wave-uniform (waves 0..3)
        const int off = (1024 + t) * 16;
        __builtin_amdgcn_global_load_lds(
            (const __attribute__((address_space(1))) unsigned int*)(wsrc + off),
            (__attribute__((address_space(3))) unsigned int*)(ldst + off),
            16, 0, 0);
    }
}

// ---------------- main: dbuf pipeline + rotating ds_read prefetch -------------
// Block = 512 thr = 8 waves x 32 px = 256 px; all waves share the SAME i.
// Per i: issue STAGE(i+1) -> basis/silu from global x -> 10 B-fragment pairs
// consumed with a ONE-PAIR-AHEAD rotating ds_read prefetch (pairs 0..7 spline,
// 8 uw, 9 rw) -> ONE barrier. The rotation hides the ~120cyc ds_read_b128
// latency under the previous pair's af-build + MFMAs (the critical path that
// pinned rounds 7-11 at ~40us: 20 JIT ds_reads x 120cyc = 2400cyc/body).
// LDS = 2x20KB. gridDim.y=16 splits i; y=0 -> out, y>0 -> partials; combine.
__global__ __launch_bounds__(512) void kan_mfma8_kernel(
    const float* __restrict__ x,               // (31, 16384)
    const unsigned char* __restrict__ wsw,     // packed B fragments (bytes)
    float* __restrict__ parts,                 // (nsplit-1) x (31,16384)
    float* __restrict__ out,                   // (31, 16384)
    int nsplit)
{
    const int t = threadIdx.x;
    const int l = t & 63;
    const int w = t >> 6;                      // 0..7
    const int pix0 = blockIdx.x * 256;
    const int csize = (IN_C + nsplit - 1) / nsplit;
    const int ibase = blockIdx.y * csize;
    const int ni = min(csize, IN_C - ibase);

    __shared__ __align__(16) unsigned char wlds[2][CHUNK_BYTES]; // 40 KB, reused for Y

    const int n0 = w * 32;

    // x~ fragments straight from global (L2-resident, once per block).
    float xf[2][8];
    bf16x8 ax[2];
#pragma unroll
    for (int mt = 0; mt < 2; ++mt) {
        const int row = pix0 + n0 + mt * 16 + (l & 15);
        const int cb = (l >> 4) * 8;
#pragma unroll
        for (int j = 0; j < 8; ++j) {
            const int c = cb + j;
            xf[mt][j] = (c < IN_C) ? x[c * NPIX + row] : 1.0f;   // x~[31] = 1
        }
#pragma unroll
        for (int j = 0; j < 8; ++j) ax[mt][j] = f2bf(xf[mt][j]);
    }

    f32x4 Y[2][2];
#pragma unroll
    for (int mt = 0; mt < 2; ++mt)
#pragma unroll
        for (int nt = 0; nt < 2; ++nt) Y[mt][nt] = (f32x4){0.f, 0.f, 0.f, 0.f};

    // prologue: stage first chunk, wait for it once
    stage_i(wsw + (size_t)ibase * CHUNK_BYTES, wlds[0], t);
    __syncthreads();

#pragma unroll 1
    for (int tt_i = 0; tt_i < ni; ++tt_i) {
        const int i = ibase + tt_i;

        // (0) per-i x loads FIRST (L2 latency overlaps everything below)
        const float xv0 = x[i * NPIX + pix0 + n0 + (l & 15)];
        const float xv1 = x[i * NPIX + pix0 + n0 + 16 + (l & 15)];

        // (1) issue next stage (in flight across this body's compute)
        if (tt_i + 1 < ni)
            stage_i(wsw + (size_t)(i + 1) * CHUNK_BYTES, wlds[(tt_i + 1) & 1], t);

        const bf16x8* wb16 = (const bf16x8*)(wlds[tt_i & 1]);

        // (2) prefetch pair 0 from LDS (buffer is valid since prev barrier)
        bf16x8 pb0 = wb16[0 * 64 + l];
        bf16x8 pb1 = wb16[1 * 64 + l];

        // (3) basis + silu*x~ (VALU; overlaps DMA + ds_read + global loads)
        float bas[2][8];
        bf16x8 arw[2];
#pragma unroll
        for (int mt = 0; mt < 2; ++mt) {
            const float xv = (mt == 0) ? xv0 : xv1;
            const float tb = (xv + 2.2f) * 2.5f;
            const float jf = floorf(tb);
            const float u  = tb - jf;
            const int  jj  = (int)jf;
            const float u2 = u * u, u3 = u2 * u;
            const float b0v = u3 * (1.f / 6.f);
            const float b1v = (-3.f * u3 + 3.f * u2 + 3.f * u + 1.f) * (1.f / 6.f);
            const float b2v = (3.f * u3 - 6.f * u2 + 4.f) * (1.f / 6.f);
            const float omu = 1.f - u;
            const float b3v = omu * omu * omu * (1.f / 6.f);
#pragma unroll
            for (int m = 0; m < 8; ++m) {
                const int d = jj - m;
                bas[mt][m] = (d == 0) ? b0v : (d == 1) ? b1v : (d == 2) ? b2v
                           : (d == 3) ? b3v : 0.f;
            }
            const float sil = xv / (1.f + __expf(-xv));
#pragma unroll
            for (int j = 0; j < 8; ++j) arw[mt][j] = f2bf(sil * xf[mt][j]);
        }

        f32x4 SP[2][2], UW[2][2];
#pragma unroll
        for (int mt = 0; mt < 2; ++mt)
#pragma unroll
            for (int nt = 0; nt < 2; ++nt) {
                SP[mt][nt] = (f32x4){0.f, 0.f, 0.f, 0.f};
                UW[mt][nt] = (f32x4){0.f, 0.f, 0.f, 0.f};
            }

        // (4) 10 pairs, one-ahead rotating prefetch:
        //     p in [0,8): spline (A = bas[p]*x~);  p==8: uw (A = ax);
        //     p==9: rw (A = arw, accumulate into Y).
#pragma unroll
        for (int p = 0; p < 10; ++p) {
            const bf16x8 b0 = pb0;
            const bf16x8 b1 = pb1;
            if (p < 9) {                       // prefetch next pair EARLY
                pb0 = wb16[((p + 1) * 2 + 0) * 64 + l];
                pb1 = wb16[((p + 1) * 2 + 1) * 64 + l];
            }
            if (p < 8) {
#pragma unroll
                for (int mt = 0; mt < 2; ++mt) {
                    bf16x8 af;
#pragma unroll
                    for (int j = 0; j < 8; ++j) af[j] = f2bf(bas[mt][p] * xf[mt][j]);
                    SP[mt][0] = __builtin_amdgcn_mfma_f32_16x16x32_bf16(af, b0, SP[mt][0], 0, 0, 0);
                    SP[mt][1] = __builtin_amdgcn_mfma_f32_16x16x32_bf16(af, b1, SP[mt][1], 0, 0, 0);
                }
            } else if (p == 8) {
#pragma unroll
                for (int mt = 0; mt < 2; ++mt) {
                    UW[mt][0] = __builtin_amdgcn_mfma_f32_16x16x32_bf16(ax[mt], b0, UW[mt][0], 0, 0, 0);
                    UW[mt][1] = __builtin_amdgcn_mfma_f32_16x16x32_bf16(ax[mt], b1, UW[mt][1], 0, 0, 0);
                }
            } else {
#pragma unroll
                for (int mt = 0; mt < 2; ++mt) {
                    Y[mt][0] = __builtin_amdgcn_mfma_f32_16x16x32_bf16(arw[mt], b0, Y[mt][0], 0, 0, 0);
                    Y[mt][1] = __builtin_amdgcn_mfma_f32_16x16x32_bf16(arw[mt], b1, Y[mt][1], 0, 0, 0);
                }
            }
        }

        // (5) Y += UW * SP (identical fragment layout)
#pragma unroll
        for (int mt = 0; mt < 2; ++mt)
#pragma unroll
            for (int nt = 0; nt < 2; ++nt)
#pragma unroll
                for (int r = 0; r < 4; ++r)
                    Y[mt][nt][r] = fmaf(UW[mt][nt][r], SP[mt][nt][r], Y[mt][nt][r]);

        // (6) ONE barrier per i: drains vmcnt (next buf staged) + read-ordering
        __syncthreads();
    }

    // ---- gather Y into wlds (free now) for coalesced store ----
    float* yb = (float*)wlds;   // 256*33 floats = 33.8 KB <= 40 KB
#pragma unroll
    for (int mt = 0; mt < 2; ++mt)
#pragma unroll
        for (int nt = 0; nt < 2; ++nt)
#pragma unroll
            for (int r = 0; r < 4; ++r) {
                const int p = n0 + mt * 16 + (l >> 4) * 4 + r;
                const int o = nt * 16 + (l & 15);
                if (o < OUT_C) yb[p * 33 + o] = Y[mt][nt][r];
            }
    __syncthreads();

    float* dst = (blockIdx.y == 0) ? out
               : (parts + (size_t)(blockIdx.y - 1) * OUT_C * NPIX);
    for (int idx = t; idx < 256 * OUT_C; idx += 512) {
        const int n = idx & 255, o = idx >> 8;
        dst[o * NPIX + pix0 + n] = yb[n * 33 + o];
    }
}

// ---------------- combine: out += sum of npart partials (vectorized) ----------
__global__ __launch_bounds__(256) void kan_combine_kernel(
    float* __restrict__ out, const float* __restrict__ parts, int npart)
{
    const int e = blockIdx.x * 256 + threadIdx.x;   // float4 index
    const int nv = (OUT_C * NPIX) / 4;
    if (e < nv) {
        f32x4 a = ((const f32x4*)out)[e];
        for (int j = 0; j < npart; ++j)
            a += ((const f32x4*)parts)[e + (size_t)j * nv];
        ((f32x4*)out)[e] = a;
    }
}

extern "C" void kernel_launch(void* const* d_in, const int* in_sizes, int n_in,
                              void* d_out, int out_size, void* d_ws, size_t ws_size,
                              hipStream_t stream) {
    const float* x  = (const float*)d_in[0];
    const float* gw = (const float*)d_in[1];
    const float* gb = (const float*)d_in[2];
    float* out = (float*)d_out;
    unsigned short* ws = (unsigned short*)d_ws;
    float* parts = (float*)((char*)d_ws + PART_OFF);

    // 16-way i-split needs 15 f32 partials (30.7 MB); fall back if ws is small
    // (deterministic: depends only on ws_size).
    const size_t part_bytes = (size_t)OUT_C * NPIX * 4;
    int nsplit = 16;
    if (ws_size < PART_OFF + 15 * part_bytes) nsplit = 8;
    if (ws_size < PART_OFF + 7 * part_bytes)  nsplit = 4;

    hipLaunchKernelGGL(kan_prep_kernel, dim3(620), dim3(64), 0, stream, gw, gb, ws);
    hipLaunchKernelGGL(kan_mfma8_kernel, dim3(NPIX / 256, nsplit), dim3(512), 0, stream,
                       x, (const unsigned char*)d_ws, parts, out, nsplit);
    const int nv = (OUT_C * NPIX) / 4;                 // 126976
    hipLaunchKernelGGL(kan_combine_kernel, dim3((nv + 255) / 256), dim3(256), 0, stream,
                       out, parts, nsplit - 1);
}

// Round 14
// 46.368 us; speedup vs baseline: 1.0619x; 1.0619x over previous
//
#include <hip/hip_runtime.h>
#include <hip/hip_bf16.h>
#include <math.h>

#define IN_C 31
#define OUT_C 31
#define NPIX 16384
#define UW_OFF 7688
#define RW_OFF 8649
#define PART_OFF (640 * 1024)  // ws byte offset of partial-Y buffers (weights use 620 KB)
#define CHUNK_BYTES 20480      // 20 KB of packed B-fragments per input channel i

typedef __attribute__((ext_vector_type(8))) _Float16 f16x8;
typedef __attribute__((ext_vector_type(4))) float f32x4;

__device__ inline short f2h(float f) {            // prep kernel only (cold): RNE
    union { _Float16 h; short s; } cv;
    cv.h = (_Float16)f;
    return cv.s;
}

// ---------------- prep: pack generator weights into MFMA B-fragment chunks ----
// ws layout: for i in [0,31): 20 chunks of 1 KB (20 KB per i, 620 KB total):
//   pairs 0..7 : spline B, chunk = kc*2 + nt  (kc in [0,8), nt in {0,1})
//   pair 8 (chunks 16,17) : uw B;  pair 9 (chunks 18,19) : rw B
// Storage is now FP16 (same byte layout as the bf16 version).
__global__ __launch_bounds__(64) void kan_prep_kernel(
    const float* __restrict__ gw, const float* __restrict__ gb,
    unsigned short* __restrict__ ws)
{
    const int blk = blockIdx.x;          // 31*20 = 620
    const int i   = blk / 20;
    const int ch  = blk % 20;
    const int l   = threadIdx.x;
    const int col = l & 15;
    const int krow = l >> 4;
    const int o = (ch & 1) * 16 + col;

    int p;
    if (ch < 16)      p = (i * 31 + o) * 8 + (ch >> 1);
    else if (ch < 18) p = UW_OFF + i * 31 + o;
    else              p = RW_OFF + i * 31 + o;

    short v8[8];
#pragma unroll
    for (int j = 0; j < 8; ++j) {
        const int c = krow * 8 + j;
        float v = 0.f;
        if (o < OUT_C) v = (c < IN_C) ? gw[p * 31 + c] : gb[p];
        v8[j] = f2h(v);
    }
    *(f16x8*)&ws[(blk * 64 + l) * 8] = *(f16x8*)v8;
}

// Stage one i's 20 KB chunk into LDS via async global->LDS DMA, 512 threads:
// 1280 16B slots: 2 full passes (1024) + waves 0..3 take the tail (256).
__device__ __forceinline__ void stage_i(const unsigned char* wsrc,
                                        unsigned char* ldst, int t) {
#pragma unroll
    for (int k = 0; k < 2; ++k) {
        const int off = (k * 512 + t) * 16;
        __builtin_amdgcn_global_load_lds(
            (const __attribute__((address_space(1))) unsigned int*)(wsrc + off),
            (__attribute__((address_space(3))) unsigned int*)(ldst + off),
            16, 0, 0);
    }
    if (t < 256) {                       // wave-uniform (waves 0..3)
        const int off = (1024 + t) * 16;
        __builtin_amdgcn_global_load_lds(
            (const __attribute__((address_space(1))) unsigned int*)(wsrc + off),
            (__attribute__((address_space(3))) unsigned int*)(ldst + off),
            16, 0, 0);
    }
}

// ---------------- main: R12 structure, FP16 math (hardware cvt + pk_mul) ------
// Block = 512 thr = 8 waves x 32 px = 256 px; all waves share the SAME i.
// Per i: issue STAGE(i+1) -> basis/silu -> 10 B-fragment pairs with one-ahead
// rotating ds_read prefetch -> ONE barrier. Change vs R12: bf16 -> fp16.
// A-fragment rebuild is now af = xv8f * basf[p] (4 v_pk_mul_f16, ZERO
// per-element converts) vs 8 mul + 8 software-RNE bf16 converts -- the
// ~1500 VALU-cyc/body that pinned rounds 7-12 at ~40us.
__global__ __launch_bounds__(512) void kan_mfma10_kernel(
    const float* __restrict__ x,               // (31, 16384)
    const unsigned char* __restrict__ wsw,     // packed B fragments (bytes)
    float* __restrict__ parts,                 // (nsplit-1) x (31,16384)
    float* __restrict__ out,                   // (31, 16384)
    int nsplit)
{
    const int t = threadIdx.x;
    const int l = t & 63;
    const int w = t >> 6;                      // 0..7
    const int pix0 = blockIdx.x * 256;
    const int csize = (IN_C + nsplit - 1) / nsplit;
    const int ibase = blockIdx.y * csize;
    const int ni = min(csize, IN_C - ibase);

    __shared__ __align__(16) unsigned char wlds[2][CHUNK_BYTES]; // 40 KB, reused for Y

    const int n0 = w * 32;

    // x~ fragments straight from global, converted to f16 ONCE per block.
    f16x8 xv8f[2];
#pragma unroll
    for (int mt = 0; mt < 2; ++mt) {
        const int row = pix0 + n0 + mt * 16 + (l & 15);
        const int cb = (l >> 4) * 8;
#pragma unroll
        for (int j = 0; j < 8; ++j) {
            const int c = cb + j;
            const float v = (c < IN_C) ? x[c * NPIX + row] : 1.0f;  // x~[31] = 1
            xv8f[mt][j] = (_Float16)v;       // v_cvt_f16_f32 (hardware, RNE)
        }
    }

    f32x4 Y[2][2];
#pragma unroll
    for (int mt = 0; mt < 2; ++mt)
#pragma unroll
        for (int nt = 0; nt < 2; ++nt) Y[mt][nt] = (f32x4){0.f, 0.f, 0.f, 0.f};

    // prologue: stage first chunk, wait for it once
    stage_i(wsw + (size_t)ibase * CHUNK_BYTES, wlds[0], t);
    __syncthreads();

#pragma unroll 1
    for (int tt_i = 0; tt_i < ni; ++tt_i) {
        const int i = ibase + tt_i;

        // (0) per-i x loads FIRST (L2 latency overlaps everything below)
        const float xv0 = x[i * NPIX + pix0 + n0 + (l & 15)];
        const float xv1 = x[i * NPIX + pix0 + n0 + 16 + (l & 15)];

        // (1) issue next stage (in flight across this body's compute)
        if (tt_i + 1 < ni)
            stage_i(wsw + (size_t)(i + 1) * CHUNK_BYTES, wlds[(tt_i + 1) & 1], t);

        const unsigned char* wb = wlds[tt_i & 1];

        // (2) prefetch pair 0 from LDS (buffer is valid since prev barrier)
        f16x8 pb0 = *(const f16x8*)(wb + (0 * 64 + l) * 16);
        f16x8 pb1 = *(const f16x8*)(wb + (1 * 64 + l) * 16);

        // (3) basis + silu (f32 VALU), then single f16 casts
        _Float16 basf[2][8];
        f16x8 arwf[2];
#pragma unroll
        for (int mt = 0; mt < 2; ++mt) {
            const float xv = (mt == 0) ? xv0 : xv1;
            const float tb = (xv + 2.2f) * 2.5f;
            const float jf = floorf(tb);
            const float u  = tb - jf;
            const int  jj  = (int)jf;
            const float u2 = u * u, u3 = u2 * u;
            const float b0v = u3 * (1.f / 6.f);
            const float b1v = (-3.f * u3 + 3.f * u2 + 3.f * u + 1.f) * (1.f / 6.f);
            const float b2v = (3.f * u3 - 6.f * u2 + 4.f) * (1.f / 6.f);
            const float omu = 1.f - u;
            const float b3v = omu * omu * omu * (1.f / 6.f);
#pragma unroll
            for (int m = 0; m < 8; ++m) {
                const int d = jj - m;
                const float bv = (d == 0) ? b0v : (d == 1) ? b1v : (d == 2) ? b2v
                               : (d == 3) ? b3v : 0.f;
                basf[mt][m] = (_Float16)bv;  // 1 hw cvt each (16/body)
            }
            const float sil = xv / (1.f + __expf(-xv));
            arwf[mt] = xv8f[mt] * (_Float16)sil;   // 4 v_pk_mul_f16 + 1 cvt
        }

        f32x4 SP[2][2], UW[2][2];
#pragma unroll
        for (int mt = 0; mt < 2; ++mt)
#pragma unroll
            for (int nt = 0; nt < 2; ++nt) {
                SP[mt][nt] = (f32x4){0.f, 0.f, 0.f, 0.f};
                UW[mt][nt] = (f32x4){0.f, 0.f, 0.f, 0.f};
            }

        // (4) 10 pairs, one-ahead rotating prefetch:
        //     p in [0,8): spline (A = basf[p] * xv8f, pure pk_mul);
        //     p==8: uw (A = xv8f);  p==9: rw (A = arwf, accumulate into Y).
#pragma unroll
        for (int p = 0; p < 10; ++p) {
            const f16x8 b0 = pb0;
            const f16x8 b1 = pb1;
            if (p < 9) {                       // prefetch next pair EARLY
                pb0 = *(const f16x8*)(wb + (((p + 1) * 2 + 0) * 64 + l) * 16);
                pb1 = *(const f16x8*)(wb + (((p + 1) * 2 + 1) * 64 + l) * 16);
            }
            if (p < 8) {
#pragma unroll
                for (int mt = 0; mt < 2; ++mt) {
                    const f16x8 af = xv8f[mt] * basf[mt][p];   // 4 pk_mul, no cvt
                    SP[mt][0] = __builtin_amdgcn_mfma_f32_16x16x32_f16(af, b0, SP[mt][0], 0, 0, 0);
                    SP[mt][1] = __builtin_amdgcn_mfma_f32_16x16x32_f16(af, b1, SP[mt][1], 0, 0, 0);
                }
            } else if (p == 8) {
#pragma unroll
                for (int mt = 0; mt < 2; ++mt) {
                    UW[mt][0] = __builtin_amdgcn_mfma_f32_16x16x32_f16(xv8f[mt], b0, UW[mt][0], 0, 0, 0);
                    UW[mt][1] = __builtin_amdgcn_mfma_f32_16x16x32_f16(xv8f[mt], b1, UW[mt][1], 0, 0, 0);
                }
            } else {
#pragma unroll
                for (int mt = 0; mt < 2; ++mt) {
                    Y[mt][0] = __builtin_amdgcn_mfma_f32_16x16x32_f16(arwf[mt], b0, Y[mt][0], 0, 0, 0);
                    Y[mt][1] = __builtin_amdgcn_mfma_f32_16x16x32_f16(arwf[mt], b1, Y[mt][1], 0, 0, 0);
                }
            }
        }

        // (5) Y += UW * SP (identical fragment layout)
#pragma unroll
        for (int mt = 0; mt < 2; ++mt)
#pragma unroll
            for (int nt = 0; nt < 2; ++nt)
#pragma unroll
                for (int r = 0; r < 4; ++r)
                    Y[mt][nt][r] = fmaf(UW[mt][nt][r], SP[mt][nt][r], Y[mt][nt][r]);

        // (6) ONE barrier per i: drains vmcnt (next buf staged) + read-ordering
        __syncthreads();
    }

    // ---- gather Y into wlds (free now) for coalesced store ----
    float* yb = (float*)wlds;   // 256*33 floats = 33.8 KB <= 40 KB
#pragma unroll
    for (int mt = 0; mt < 2; ++mt)
#pragma unroll
        for (int nt = 0; nt < 2; ++nt)
#pragma unroll
            for (int r = 0; r < 4; ++r) {
                const int p = n0 + mt * 16 + (l >> 4) * 4 + r;
                const int o = nt * 16 + (l & 15);
                if (o < OUT_C) yb[p * 33 + o] = Y[mt][nt][r];
            }
    __syncthreads();

    float* dst = (blockIdx.y == 0) ? out
               : (parts + (size_t)(blockIdx.y - 1) * OUT_C * NPIX);
    for (int idx = t; idx < 256 * OUT_C; idx += 512) {
        const int n = idx & 255, o = idx >> 8;
        dst[o * NPIX + pix0 + n] = yb[n * 33 + o];
    }
}

// ---------------- combine: out += sum of npart partials (vectorized) ----------
__global__ __launch_bounds__(256) void kan_combine_kernel(
    float* __restrict__ out, const float* __restrict__ parts, int npart)
{
    const int e = blockIdx.x * 256 + threadIdx.x;   // float4 index
    const int nv = (OUT_C * NPIX) / 4;
    if (e < nv) {
        f32x4 a = ((const f32x4*)out)[e];
        for (int j = 0; j < npart; ++j)
            a += ((const f32x4*)parts)[e + (size_t)j * nv];
        ((f32x4*)out)[e] = a;
    }
}

extern "C" void kernel_launch(void* const* d_in, const int* in_sizes, int n_in,
                              void* d_out, int out_size, void* d_ws, size_t ws_size,
                              hipStream_t stream) {
    const float* x  = (const float*)d_in[0];
    const float* gw = (const float*)d_in[1];
    const float* gb = (const float*)d_in[2];
    float* out = (float*)d_out;
    unsigned short* ws = (unsigned short*)d_ws;
    float* parts = (float*)((char*)d_ws + PART_OFF);

    // 16-way i-split needs 15 f32 partials (30.7 MB); fall back if ws is small
    // (deterministic: depends only on ws_size).
    const size_t part_bytes = (size_t)OUT_C * NPIX * 4;
    int nsplit = 16;
    if (ws_size < PART_OFF + 15 * part_bytes) nsplit = 8;
    if (ws_size < PART_OFF + 7 * part_bytes)  nsplit = 4;

    hipLaunchKernelGGL(kan_prep_kernel, dim3(620), dim3(64), 0, stream, gw, gb, ws);
    hipLaunchKernelGGL(kan_mfma10_kernel, dim3(NPIX / 256, nsplit), dim3(512), 0, stream,
                       x, (const unsigned char*)d_ws, parts, out, nsplit);
    const int nv = (OUT_C * NPIX) / 4;                 // 126976
    hipLaunchKernelGGL(kan_combine_kernel, dim3((nv + 255) / 256), dim3(256), 0, stream,
                       out, parts, nsplit - 1);
}

// Round 15
// 39.529 us; speedup vs baseline: 1.2456x; 1.1730x over previous
//
#include <hip/hip_runtime.h>
#include <hip/hip_bf16.h>
#include <math.h>

#define IN_C 31
#define OUT_C 31
#define NPIX 16384
#define UW_OFF 7688
#define RW_OFF 8649
#define PART_OFF (640 * 1024)  // ws byte offset of partial-Y buffers (weights use 620 KB)
#define CHUNK_BYTES 20480      // 20 KB of packed B-fragments per input channel i

typedef __attribute__((ext_vector_type(8))) _Float16 f16x8;
typedef __attribute__((ext_vector_type(4))) float f32x4;

__device__ inline short f2h(float f) {            // prep kernel only (cold): RNE
    union { _Float16 h; short s; } cv;
    cv.h = (_Float16)f;
    return cv.s;
}

// ---------------- prep: pack generator weights into MFMA B-fragment chunks ----
// ws layout: for i in [0,31): 20 chunks of 1 KB (20 KB per i, 620 KB total):
//   pairs 0..7 : spline B, chunk = kc*2 + nt  (kc in [0,8), nt in {0,1})
//   pair 8 (chunks 16,17) : uw B;  pair 9 (chunks 18,19) : rw B   (FP16)
__global__ __launch_bounds__(64) void kan_prep_kernel(
    const float* __restrict__ gw, const float* __restrict__ gb,
    unsigned short* __restrict__ ws)
{
    const int blk = blockIdx.x;          // 31*20 = 620
    const int i   = blk / 20;
    const int ch  = blk % 20;
    const int l   = threadIdx.x;
    const int col = l & 15;
    const int krow = l >> 4;
    const int o = (ch & 1) * 16 + col;

    int p;
    if (ch < 16)      p = (i * 31 + o) * 8 + (ch >> 1);
    else if (ch < 18) p = UW_OFF + i * 31 + o;
    else              p = RW_OFF + i * 31 + o;

    short v8[8];
#pragma unroll
    for (int j = 0; j < 8; ++j) {
        const int c = krow * 8 + j;
        float v = 0.f;
        if (o < OUT_C) v = (c < IN_C) ? gw[p * 31 + c] : gb[p];
        v8[j] = f2h(v);
    }
    *(f16x8*)&ws[(blk * 64 + l) * 8] = *(f16x8*)v8;
}

// Stage one i's 20 KB chunk into LDS via async global->LDS DMA, 512 threads:
// 1280 16B slots: 2 full passes (1024) + waves 0..3 take the tail (256).
__device__ __forceinline__ void stage_i(const unsigned char* wsrc,
                                        unsigned char* ldst, int t) {
#pragma unroll
    for (int k = 0; k < 2; ++k) {
        const int off = (k * 512 + t) * 16;
        __builtin_amdgcn_global_load_lds(
            (const __attribute__((address_space(1))) unsigned int*)(wsrc + off),
            (__attribute__((address_space(3))) unsigned int*)(ldst + off),
            16, 0, 0);
    }
    if (t < 256) {                       // wave-uniform (waves 0..3)
        const int off = (1024 + t) * 16;
        __builtin_amdgcn_global_load_lds(
            (const __attribute__((address_space(1))) unsigned int*)(wsrc + off),
            (__attribute__((address_space(3))) unsigned int*)(ldst + off),
            16, 0, 0);
    }
}

// ---------------- main: TWO interleaved i-bodies per wave (ILP) ---------------
// Block = 512 thr = 8 waves x 16 px = 128 px; all waves share the SAME i-pair.
// Per pair (i0,i1): stage next pair into the other 2 of 4 LDS buffers ->
// basis/silu for both i -> p-loop 0..9 issuing BOTH i's ds_reads + MFMAs
// (independent SP/UW accumulator sets = 2 independent dep-chains per wave,
// the ILP that rounds 7-14's single-chain bodies lacked) -> fold -> ONE
// barrier per 2 i's. LDS = 4x20KB = 80 KB -> 2 blocks/CU = 16 waves/CU.
// gridDim.y=4 splits i (8/8/8/7); y=0 -> out, y>0 -> partials; combine sums.
__global__ __launch_bounds__(512) void kan_mfma11_kernel(
    const float* __restrict__ x,               // (31, 16384)
    const unsigned char* __restrict__ wsw,     // packed B fragments (bytes)
    float* __restrict__ parts,                 // (nsplit-1) x (31,16384)
    float* __restrict__ out,                   // (31, 16384)
    int nsplit)
{
    const int t = threadIdx.x;
    const int l = t & 63;
    const int w = t >> 6;                      // 0..7
    const int pix0 = blockIdx.x * 128;
    const int csize = (IN_C + nsplit - 1) / nsplit;
    const int ibase = blockIdx.y * csize;
    const int iend = min(ibase + csize, IN_C);

    __shared__ __align__(16) unsigned char bufs[4][CHUNK_BYTES]; // 80 KB, reused for Y

    const int n0 = w * 16;
    const int prow = pix0 + n0 + (l & 15);     // this lane's pixel row

    // x~ fragment (f16, once per block): lane holds c = (l>>4)*8 + j
    f16x8 xv8f;
    {
        const int cb = (l >> 4) * 8;
#pragma unroll
        for (int j = 0; j < 8; ++j) {
            const int c = cb + j;
            const float v = (c < IN_C) ? x[c * NPIX + prow] : 1.0f;  // x~[31]=1
            xv8f[j] = (_Float16)v;
        }
    }

    f32x4 Y[2];
    Y[0] = (f32x4){0.f, 0.f, 0.f, 0.f};
    Y[1] = (f32x4){0.f, 0.f, 0.f, 0.f};

    // prologue: stage first i-pair
    stage_i(wsw + (size_t)ibase * CHUNK_BYTES, bufs[0], t);
    if (ibase + 1 < iend)
        stage_i(wsw + (size_t)(ibase + 1) * CHUNK_BYTES, bufs[1], t);
    __syncthreads();

    const int npairs = (iend - ibase + 1) >> 1;

#pragma unroll 1
    for (int tp = 0; tp < npairs; ++tp) {
        const int i0 = ibase + 2 * tp;
        const bool has1 = (i0 + 1) < iend;     // wave-uniform

        // stage next pair into the other buffer half
        if (tp + 1 < npairs) {
            const int nx = i0 + 2;
            unsigned char* d0 = bufs[2 * ((tp + 1) & 1)];
            stage_i(wsw + (size_t)nx * CHUNK_BYTES, d0, t);
            if (nx + 1 < iend)
                stage_i(wsw + (size_t)(nx + 1) * CHUNK_BYTES, d0 + CHUNK_BYTES, t);
        }

        // per-i x values (L2-hit; latency overlaps basis/silu below)
        const float xa = x[i0 * NPIX + prow];
        const float xb = has1 ? x[(i0 + 1) * NPIX + prow] : 0.f;

        // basis + silu for BOTH i (f32 VALU, single f16 casts)
        _Float16 basA[8], basB[8];
        f16x8 arwA, arwB;
#pragma unroll
        for (int s = 0; s < 2; ++s) {
            const float xv = (s == 0) ? xa : xb;
            const float tb = (xv + 2.2f) * 2.5f;
            const float jf = floorf(tb);
            const float u  = tb - jf;
            const int  jj  = (int)jf;
            const float u2 = u * u, u3 = u2 * u;
            const float b0v = u3 * (1.f / 6.f);
            const float b1v = (-3.f * u3 + 3.f * u2 + 3.f * u + 1.f) * (1.f / 6.f);
            const float b2v = (3.f * u3 - 6.f * u2 + 4.f) * (1.f / 6.f);
            const float omu = 1.f - u;
            const float b3v = omu * omu * omu * (1.f / 6.f);
#pragma unroll
            for (int m = 0; m < 8; ++m) {
                const int d = jj - m;
                const float bv = (d == 0) ? b0v : (d == 1) ? b1v : (d == 2) ? b2v
                               : (d == 3) ? b3v : 0.f;
                if (s == 0) basA[m] = (_Float16)bv; else basB[m] = (_Float16)bv;
            }
            const float sil = xv / (1.f + __expf(-xv));
            if (s == 0) arwA = xv8f * (_Float16)sil;
            else        arwB = xv8f * (_Float16)sil;
        }

        const unsigned char* wbA = bufs[2 * (tp & 1)];
        const unsigned char* wbB = wbA + CHUNK_BYTES;

        f32x4 SPA[2], UWA[2], SPB[2], UWB[2];
#pragma unroll
        for (int nt = 0; nt < 2; ++nt) {
            SPA[nt] = (f32x4){0.f, 0.f, 0.f, 0.f};
            UWA[nt] = (f32x4){0.f, 0.f, 0.f, 0.f};
            SPB[nt] = (f32x4){0.f, 0.f, 0.f, 0.f};
            UWB[nt] = (f32x4){0.f, 0.f, 0.f, 0.f};
        }

        // 10 pairs; both i-streams issued together (independent dep chains)
#pragma unroll
        for (int p = 0; p < 10; ++p) {
            const f16x8 a0 = *(const f16x8*)(wbA + ((p * 2 + 0) * 64 + l) * 16);
            const f16x8 a1 = *(const f16x8*)(wbA + ((p * 2 + 1) * 64 + l) * 16);
            const f16x8 c0 = *(const f16x8*)(wbB + ((p * 2 + 0) * 64 + l) * 16);
            const f16x8 c1 = *(const f16x8*)(wbB + ((p * 2 + 1) * 64 + l) * 16);
            if (p < 8) {
                const f16x8 afA = xv8f * basA[p];      // 4 v_pk_mul_f16
                SPA[0] = __builtin_amdgcn_mfma_f32_16x16x32_f16(afA, a0, SPA[0], 0, 0, 0);
                SPA[1] = __builtin_amdgcn_mfma_f32_16x16x32_f16(afA, a1, SPA[1], 0, 0, 0);
                if (has1) {
                    const f16x8 afB = xv8f * basB[p];
                    SPB[0] = __builtin_amdgcn_mfma_f32_16x16x32_f16(afB, c0, SPB[0], 0, 0, 0);
                    SPB[1] = __builtin_amdgcn_mfma_f32_16x16x32_f16(afB, c1, SPB[1], 0, 0, 0);
                }
            } else if (p == 8) {
                UWA[0] = __builtin_amdgcn_mfma_f32_16x16x32_f16(xv8f, a0, UWA[0], 0, 0, 0);
                UWA[1] = __builtin_amdgcn_mfma_f32_16x16x32_f16(xv8f, a1, UWA[1], 0, 0, 0);
                if (has1) {
                    UWB[0] = __builtin_amdgcn_mfma_f32_16x16x32_f16(xv8f, c0, UWB[0], 0, 0, 0);
                    UWB[1] = __builtin_amdgcn_mfma_f32_16x16x32_f16(xv8f, c1, UWB[1], 0, 0, 0);
                }
            } else {
                Y[0] = __builtin_amdgcn_mfma_f32_16x16x32_f16(arwA, a0, Y[0], 0, 0, 0);
                Y[1] = __builtin_amdgcn_mfma_f32_16x16x32_f16(arwA, a1, Y[1], 0, 0, 0);
                if (has1) {
                    Y[0] = __builtin_amdgcn_mfma_f32_16x16x32_f16(arwB, c0, Y[0], 0, 0, 0);
                    Y[1] = __builtin_amdgcn_mfma_f32_16x16x32_f16(arwB, c1, Y[1], 0, 0, 0);
                }
            }
        }

        // fold: Y += UW * SP for both i (identical fragment layout)
#pragma unroll
        for (int nt = 0; nt < 2; ++nt)
#pragma unroll
            for (int r = 0; r < 4; ++r) {
                Y[nt][r] = fmaf(UWA[nt][r], SPA[nt][r], Y[nt][r]);
                if (has1) Y[nt][r] = fmaf(UWB[nt][r], SPB[nt][r], Y[nt][r]);
            }

        // ONE barrier per 2 i's: drains vmcnt (next pair staged) + ordering
        __syncthreads();
    }

    // ---- gather Y into bufs (free now) for coalesced store ----
    float* yb = (float*)bufs;   // 128*33 floats = 16.9 KB << 80 KB
#pragma unroll
    for (int nt = 0; nt < 2; ++nt)
#pragma unroll
        for (int r = 0; r < 4; ++r) {
            const int p = n0 + (l >> 4) * 4 + r;
            const int o = nt * 16 + (l & 15);
            if (o < OUT_C) yb[p * 33 + o] = Y[nt][r];
        }
    __syncthreads();

    float* dst = (blockIdx.y == 0) ? out
               : (parts + (size_t)(blockIdx.y - 1) * OUT_C * NPIX);
    for (int idx = t; idx < 128 * OUT_C; idx += 512) {
        const int n = idx & 127, o = idx >> 7;
        dst[o * NPIX + pix0 + n] = yb[n * 33 + o];
    }
}

// ---------------- combine: out += sum of npart partials (vectorized) ----------
__global__ __launch_bounds__(256) void kan_combine_kernel(
    float* __restrict__ out, const float* __restrict__ parts, int npart)
{
    const int e = blockIdx.x * 256 + threadIdx.x;   // float4 index
    const int nv = (OUT_C * NPIX) / 4;
    if (e < nv) {
        f32x4 a = ((const f32x4*)out)[e];
        for (int j = 0; j < npart; ++j)
            a += ((const f32x4*)parts)[e + (size_t)j * nv];
        ((f32x4*)out)[e] = a;
    }
}

extern "C" void kernel_launch(void* const* d_in, const int* in_sizes, int n_in,
                              void* d_out, int out_size, void* d_ws, size_t ws_size,
                              hipStream_t stream) {
    const float* x  = (const float*)d_in[0];
    const float* gw = (const float*)d_in[1];
    const float* gb = (const float*)d_in[2];
    float* out = (float*)d_out;
    unsigned short* ws = (unsigned short*)d_ws;
    float* parts = (float*)((char*)d_ws + PART_OFF);

    // 4-way i-split: 3 f32 partials (6.1 MB); ws is ~268 MB (fill evidence),
    // but keep a deterministic fallback to 2 just in case.
    const size_t part_bytes = (size_t)OUT_C * NPIX * 4;
    int nsplit = 4;
    if (ws_size < PART_OFF + 3 * part_bytes) nsplit = 2;

    hipLaunchKernelGGL(kan_prep_kernel, dim3(620), dim3(64), 0, stream, gw, gb, ws);
    hipLaunchKernelGGL(kan_mfma11_kernel, dim3(NPIX / 128, nsplit), dim3(512), 0, stream,
                       x, (const unsigned char*)d_ws, parts, out, nsplit);
    const int nv = (OUT_C * NPIX) / 4;                 // 126976
    hipLaunchKernelGGL(kan_combine_kernel, dim3((nv + 255) / 256), dim3(256), 0, stream,
                       out, parts, nsplit - 1);
}